// Round 5
// baseline (300.981 us; speedup 1.0000x reference)
//
#include <hip/hip_runtime.h>
#include <math.h>

#define BATCH 256
#define DIN   5120
#define RANK  160
#define NS    16
#define NCAT  192   // RANK + NS + NS
#define GRID  480   // co-resident: <=2 blocks/CU worst-case => 512 slots >= 480

// ---------------------------------------------------------------------------
// Software grid barrier. Safe because all 480 blocks are guaranteed
// co-resident (256 thr, 16.5 KB LDS, VGPR<=256 -> >=2 blocks/CU).
// Release/acquire at AGENT scope: release flushes stores, acquire
// invalidates the reading CU's L1 so phase-crossing data is fresh.
// ---------------------------------------------------------------------------
__device__ __forceinline__ void grid_barrier(int* ctr, int nblk)
{
    __syncthreads();
    if (threadIdx.x == 0) {
        __hip_atomic_fetch_add(ctr, 1, __ATOMIC_RELEASE, __HIP_MEMORY_SCOPE_AGENT);
        while (__hip_atomic_load(ctr, __ATOMIC_ACQUIRE, __HIP_MEMORY_SCOPE_AGENT) < nblk)
            __builtin_amdgcn_s_sleep(2);
    }
    __syncthreads();
}

__device__ __forceinline__ float softplus20(float z)
{
    if (z > 20.f) return z;
    return fmaxf(z, 0.f) + log1pf(__expf(-fabsf(z)));
}

// ---------------------------------------------------------------------------
// mega: phase1 = [P|Bp|C] split-K GEMM (480 blocks = 12 tiles x 40 splits)
//       phase2 = dt GEMM + softplus (320 active blocks)
//       phase3 = SSM update + readout (1280 virtual blocks, grid-strided)
// ---------------------------------------------------------------------------
__global__ __launch_bounds__(256) void mega(
    const float* __restrict__ x, const float* __restrict__ h,
    const float* __restrict__ Wd, const float* __restrict__ Wdt,
    const float* __restrict__ bdt, const float* __restrict__ A_log,
    const float* __restrict__ WB, const float* __restrict__ WC,
    const float* __restrict__ Dv,
    int* __restrict__ bar, float* __restrict__ P,
    float* __restrict__ Bp, float* __restrict__ Cc,
    float* __restrict__ dtb, float* __restrict__ y)
{
    __shared__ float sA[32][64];
    __shared__ float sW[32][64];
    __shared__ float sB4[4][NS];
    __shared__ float sC4[4][NS];

    const int t   = threadIdx.x;
    const int blk = blockIdx.x;

    // ---------------- phase 1: k1 split-K GEMM ----------------
    {
        const int m0 = (blk & 3) * 64;
        const int n0 = ((blk >> 2) % 3) * 64;
        const int k0 = (blk / 12) * 128;
        const int tm = (t >> 4) * 4;
        const int tn = (t & 15) * 4;
        const int lm  = t >> 2;
        const int lk  = (t & 3) * 8;
        const int ln  = t & 63;
        const int lkb = (t >> 6) * 8;

        const float* wsrc; int wstr;
        {
            const int c = n0 + ln;
            if (c < RANK)            { wsrc = Wd + c;                wstr = RANK; }
            else if (c < RANK + NS)  { wsrc = WB + (c - RANK);       wstr = NS;   }
            else                     { wsrc = WC + (c - RANK - NS);  wstr = NS;   }
        }

        float acc[4][4] = {{0.f}};

        for (int ks = 0; ks < 4; ++ks) {
            const int kb = k0 + ks * 32;
            {
                const float* src = x + (size_t)(m0 + lm) * DIN + kb + lk;
                const float4 a0 = *(const float4*)src;
                const float4 a1 = *(const float4*)(src + 4);
                sA[lk+0][lm]=a0.x; sA[lk+1][lm]=a0.y; sA[lk+2][lm]=a0.z; sA[lk+3][lm]=a0.w;
                sA[lk+4][lm]=a1.x; sA[lk+5][lm]=a1.y; sA[lk+6][lm]=a1.z; sA[lk+7][lm]=a1.w;
            }
            {
                const float* wp = wsrc + (size_t)(kb + lkb) * wstr;
                #pragma unroll
                for (int i = 0; i < 8; ++i) { sW[lkb + i][ln] = *wp; wp += wstr; }
            }
            __syncthreads();
            #pragma unroll
            for (int k = 0; k < 32; ++k) {
                const float4 a = *(const float4*)&sA[k][tm];
                const float4 b = *(const float4*)&sW[k][tn];
                acc[0][0] += a.x*b.x; acc[0][1] += a.x*b.y; acc[0][2] += a.x*b.z; acc[0][3] += a.x*b.w;
                acc[1][0] += a.y*b.x; acc[1][1] += a.y*b.y; acc[1][2] += a.y*b.z; acc[1][3] += a.y*b.w;
                acc[2][0] += a.z*b.x; acc[2][1] += a.z*b.y; acc[2][2] += a.z*b.z; acc[2][3] += a.z*b.w;
                acc[3][0] += a.w*b.x; acc[3][1] += a.w*b.y; acc[3][2] += a.w*b.z; acc[3][3] += a.w*b.w;
            }
            __syncthreads();
        }

        #pragma unroll
        for (int i = 0; i < 4; ++i) {
            const int gm = m0 + tm + i;
            #pragma unroll
            for (int j = 0; j < 4; ++j) {
                const int c = n0 + tn + j;
                float* dst;
                if (c < RANK)           dst = P  + gm * RANK + c;
                else if (c < RANK + NS) dst = Bp + gm * NS + (c - RANK);
                else                    dst = Cc + gm * NS + (c - RANK - NS);
                atomicAdd(dst, acc[i][j]);
            }
        }
    }

    grid_barrier(&bar[0], GRID);

    // ---------------- phase 2: dt GEMM + softplus ----------------
    if (blk < 320) {
        const int m0 = (blk & 3) * 64;
        const int n0 = (blk >> 2) * 64;
        const int tm = (t >> 4) * 4;
        const int tn = (t & 15) * 4;
        const int lm  = t >> 2;
        const int lk  = (t & 3) * 8;
        const int ln  = t & 63;
        const int lkb = (t >> 6) * 8;

        float acc[4][4] = {{0.f}};

        for (int ks = 0; ks < 5; ++ks) {
            const int kb = ks * 32;
            {
                const float* src = P + (size_t)(m0 + lm) * RANK + kb + lk;
                const float4 a0 = *(const float4*)src;
                const float4 a1 = *(const float4*)(src + 4);
                sA[lk+0][lm]=a0.x; sA[lk+1][lm]=a0.y; sA[lk+2][lm]=a0.z; sA[lk+3][lm]=a0.w;
                sA[lk+4][lm]=a1.x; sA[lk+5][lm]=a1.y; sA[lk+6][lm]=a1.z; sA[lk+7][lm]=a1.w;
            }
            {
                const float* wp = Wdt + (size_t)(kb + lkb) * DIN + n0 + ln;
                #pragma unroll
                for (int i = 0; i < 8; ++i) { sW[lkb + i][ln] = wp[(size_t)i * DIN]; }
            }
            __syncthreads();
            #pragma unroll
            for (int k = 0; k < 32; ++k) {
                const float4 a = *(const float4*)&sA[k][tm];
                const float4 b = *(const float4*)&sW[k][tn];
                acc[0][0] += a.x*b.x; acc[0][1] += a.x*b.y; acc[0][2] += a.x*b.z; acc[0][3] += a.x*b.w;
                acc[1][0] += a.y*b.x; acc[1][1] += a.y*b.y; acc[1][2] += a.y*b.z; acc[1][3] += a.y*b.w;
                acc[2][0] += a.z*b.x; acc[2][1] += a.z*b.y; acc[2][2] += a.z*b.z; acc[2][3] += a.z*b.w;
                acc[3][0] += a.w*b.x; acc[3][1] += a.w*b.y; acc[3][2] += a.w*b.z; acc[3][3] += a.w*b.w;
            }
            __syncthreads();
        }

        const float4 bz = *(const float4*)&bdt[n0 + tn];
        #pragma unroll
        for (int i = 0; i < 4; ++i) {
            const int gm = m0 + tm + i;
            float4 o;
            o.x = softplus20(acc[i][0] + bz.x);
            o.y = softplus20(acc[i][1] + bz.y);
            o.z = softplus20(acc[i][2] + bz.z);
            o.w = softplus20(acc[i][3] + bz.w);
            *(float4*)&dtb[(size_t)gm * DIN + n0 + tn] = o;
        }
    }

    grid_barrier(&bar[1], GRID);

    // ---------------- phase 3: SSM update + readout ----------------
    for (int vb = blk; vb < 1280; vb += GRID) {
        const int d  = (vb % 20) * 256 + t;
        const int b0 = (vb / 20) * 4;

        __syncthreads();   // protect sB4/sC4 from previous iteration's readers
        if (t < 64)                    sB4[t >> 4][t & 15] = Bp[b0 * NS + t];
        else if (t < 128) { int u = t - 64; sC4[u >> 4][u & 15] = Cc[b0 * NS + u]; }
        __syncthreads();

        float A2[NS];
        {
            const float4* ap = (const float4*)(A_log + (size_t)d * NS);
            #pragma unroll
            for (int q = 0; q < 4; ++q) {
                const float4 a4 = ap[q];
                A2[4*q+0] = -1.442695041f * __expf(a4.x);
                A2[4*q+1] = -1.442695041f * __expf(a4.y);
                A2[4*q+2] = -1.442695041f * __expf(a4.z);
                A2[4*q+3] = -1.442695041f * __expf(a4.w);
            }
        }
        const float dv = Dv[d];

        #pragma unroll
        for (int b = 0; b < 4; ++b) {
            const int gb = b0 + b;
            const float dtv = dtb[(size_t)gb * DIN + d];
            const float xv  = x[(size_t)gb * DIN + d];
            const float dtx = dtv * xv;
            const float4* hp = (const float4*)(h + ((size_t)gb * DIN + d) * NS);
            float s = 0.f;
            #pragma unroll
            for (int q = 0; q < 4; ++q) {
                const float4 h4 = hp[q];
                s += (exp2f(dtv * A2[4*q+0]) * h4.x + dtx * sB4[b][4*q+0]) * sC4[b][4*q+0];
                s += (exp2f(dtv * A2[4*q+1]) * h4.y + dtx * sB4[b][4*q+1]) * sC4[b][4*q+1];
                s += (exp2f(dtv * A2[4*q+2]) * h4.z + dtx * sB4[b][4*q+2]) * sC4[b][4*q+2];
                s += (exp2f(dtv * A2[4*q+3]) * h4.w + dtx * sB4[b][4*q+3]) * sC4[b][4*q+3];
            }
            y[(size_t)gb * DIN + d] = s + xv * dv;
        }
    }
}

// ---------------------------------------------------------------------------
extern "C" void kernel_launch(void* const* d_in, const int* in_sizes, int n_in,
                              void* d_out, int out_size, void* d_ws, size_t ws_size,
                              hipStream_t stream)
{
    const float* x     = (const float*)d_in[0];
    const float* h     = (const float*)d_in[1];
    const float* Wd    = (const float*)d_in[2];
    const float* Wdt   = (const float*)d_in[3];
    const float* bdt   = (const float*)d_in[4];
    const float* A_log = (const float*)d_in[5];
    const float* WB    = (const float*)d_in[6];
    const float* WC    = (const float*)d_in[7];
    const float* Dv    = (const float*)d_in[8];
    float* out = (float*)d_out;

    // ws layout: bar[16] (ints) | P (256x160) | Bp (256x16) | C (256x16) | dt (256x5120)
    int*   bar = (int*)d_ws;
    float* P   = (float*)d_ws + 16;
    float* Bp  = P  + BATCH * RANK;
    float* Cc  = Bp + BATCH * NS;
    float* dtb = Cc + BATCH * NS;

    // zero barrier counters + atomic-accumulation targets in one small memset
    hipMemsetAsync(d_ws, 0, (16 + (size_t)BATCH * NCAT) * sizeof(float), stream);

    mega<<<dim3(GRID), 256, 0, stream>>>(x, h, Wd, Wdt, bdt, A_log, WB, WC, Dv,
                                         bar, P, Bp, Cc, dtb, out);
}

// Round 6
// 182.235 us; speedup vs baseline: 1.6516x; 1.6516x over previous
//
#include <hip/hip_runtime.h>
#include <math.h>

#define BATCH 256
#define DIN   5120
#define RANK  160
#define NS    16
#define NCAT  192   // RANK + NS + NS
#define NSPLIT 40   // k-splits for k1

// ---------------------------------------------------------------------------
// k1a: partial[z] = x(256x5120) @ [W_delta | W_B | W_C] over k-chunk z.
// Split-K (40 chunks of 128), 64x64 tile, 4x4 reg tile. NO atomics:
// each block stores its tile into psum[z][256][192] with plain float4 stores.
// ---------------------------------------------------------------------------
__global__ __launch_bounds__(256) void k1a_gemm(
    const float* __restrict__ x, const float* __restrict__ Wd,
    const float* __restrict__ WB, const float* __restrict__ WC,
    float* __restrict__ psum)
{
    __shared__ float xT[32][64];   // [k][m]
    __shared__ float Wt[32][64];   // [k][n]
    const int t  = threadIdx.x;
    const int m0 = blockIdx.x * 64;
    const int n0 = blockIdx.y * 64;
    const int z  = blockIdx.z;
    const int k0 = z * 128;
    const int tm = (t >> 4) * 4;
    const int tn = (t & 15) * 4;

    const int lm  = t >> 2;
    const int lk  = (t & 3) * 8;
    const int ln  = t & 63;
    const int lkb = (t >> 6) * 8;

    const float* wsrc; int wstr;
    {
        const int c = n0 + ln;
        if (c < RANK)            { wsrc = Wd + c;                wstr = RANK; }
        else if (c < RANK + NS)  { wsrc = WB + (c - RANK);       wstr = NS;   }
        else                     { wsrc = WC + (c - RANK - NS);  wstr = NS;   }
    }

    float acc[4][4] = {{0.f}};

    for (int ks = 0; ks < 4; ++ks) {
        const int kb = k0 + ks * 32;
        {
            const float* src = x + (size_t)(m0 + lm) * DIN + kb + lk;
            const float4 a0 = *(const float4*)src;
            const float4 a1 = *(const float4*)(src + 4);
            xT[lk+0][lm]=a0.x; xT[lk+1][lm]=a0.y; xT[lk+2][lm]=a0.z; xT[lk+3][lm]=a0.w;
            xT[lk+4][lm]=a1.x; xT[lk+5][lm]=a1.y; xT[lk+6][lm]=a1.z; xT[lk+7][lm]=a1.w;
        }
        {
            const float* wp = wsrc + (size_t)(kb + lkb) * wstr;
            #pragma unroll
            for (int i = 0; i < 8; ++i) { Wt[lkb + i][ln] = *wp; wp += wstr; }
        }
        __syncthreads();
        #pragma unroll
        for (int k = 0; k < 32; ++k) {
            const float4 a = *(const float4*)&xT[k][tm];
            const float4 b = *(const float4*)&Wt[k][tn];
            acc[0][0] += a.x*b.x; acc[0][1] += a.x*b.y; acc[0][2] += a.x*b.z; acc[0][3] += a.x*b.w;
            acc[1][0] += a.y*b.x; acc[1][1] += a.y*b.y; acc[1][2] += a.y*b.z; acc[1][3] += a.y*b.w;
            acc[2][0] += a.z*b.x; acc[2][1] += a.z*b.y; acc[2][2] += a.z*b.z; acc[2][3] += a.z*b.w;
            acc[3][0] += a.w*b.x; acc[3][1] += a.w*b.y; acc[3][2] += a.w*b.z; acc[3][3] += a.w*b.w;
        }
        __syncthreads();
    }

    float* dst = psum + (size_t)z * (BATCH * NCAT);
    #pragma unroll
    for (int i = 0; i < 4; ++i) {
        const int gm = m0 + tm + i;
        float4 o; o.x = acc[i][0]; o.y = acc[i][1]; o.z = acc[i][2]; o.w = acc[i][3];
        *(float4*)&dst[(size_t)gm * NCAT + n0 + tn] = o;
    }
}

// ---------------------------------------------------------------------------
// k1r: reduce the 40 partials -> P (256x160), Bp (256x16), Cc (256x16).
// 192 blocks x 256 threads, one output element each, 40 coalesced adds.
// ---------------------------------------------------------------------------
__global__ __launch_bounds__(256) void k1r_reduce(
    const float* __restrict__ psum, float* __restrict__ P,
    float* __restrict__ Bp, float* __restrict__ Cc)
{
    const int o = blockIdx.x * 256 + threadIdx.x;   // 0..49151
    float s = 0.f;
    #pragma unroll 8
    for (int z = 0; z < NSPLIT; ++z) s += psum[(size_t)z * (BATCH * NCAT) + o];
    const int gm = o / NCAT;
    const int gc = o - gm * NCAT;
    if (gc < RANK)           P [gm * RANK + gc]             = s;
    else if (gc < RANK + NS) Bp[gm * NS   + gc - RANK]      = s;
    else                     Cc[gm * NS   + gc - RANK - NS] = s;
}

__device__ __forceinline__ float softplus20(float z)
{
    if (z > 20.f) return z;
    return fmaxf(z, 0.f) + log1pf(__expf(-fabsf(z)));
}

// ---------------------------------------------------------------------------
// k2a: dt(256x5120) = softplus(P(256x160) @ W_dt(160x5120) + b_dt)
// 64x64 tile, K=160 in 5 stages of 32, fused bias+softplus. grid (4,80).
// ---------------------------------------------------------------------------
__global__ __launch_bounds__(256) void k2a_gemm(
    const float* __restrict__ P, const float* __restrict__ Wdt,
    const float* __restrict__ bdt, float* __restrict__ dtb)
{
    __shared__ float aT[32][64];
    __shared__ float Bt[32][64];
    const int t  = threadIdx.x;
    const int m0 = blockIdx.x * 64;
    const int n0 = blockIdx.y * 64;
    const int tm = (t >> 4) * 4;
    const int tn = (t & 15) * 4;

    const int lm  = t >> 2;
    const int lk  = (t & 3) * 8;
    const int ln  = t & 63;
    const int lkb = (t >> 6) * 8;

    float acc[4][4] = {{0.f}};

    for (int ks = 0; ks < 5; ++ks) {
        const int kb = ks * 32;
        {
            const float* src = P + (size_t)(m0 + lm) * RANK + kb + lk;
            const float4 a0 = *(const float4*)src;
            const float4 a1 = *(const float4*)(src + 4);
            aT[lk+0][lm]=a0.x; aT[lk+1][lm]=a0.y; aT[lk+2][lm]=a0.z; aT[lk+3][lm]=a0.w;
            aT[lk+4][lm]=a1.x; aT[lk+5][lm]=a1.y; aT[lk+6][lm]=a1.z; aT[lk+7][lm]=a1.w;
        }
        {
            const float* wp = Wdt + (size_t)(kb + lkb) * DIN + n0 + ln;
            #pragma unroll
            for (int i = 0; i < 8; ++i) { Bt[lkb + i][ln] = wp[(size_t)i * DIN]; }
        }
        __syncthreads();
        #pragma unroll
        for (int k = 0; k < 32; ++k) {
            const float4 a = *(const float4*)&aT[k][tm];
            const float4 b = *(const float4*)&Bt[k][tn];
            acc[0][0] += a.x*b.x; acc[0][1] += a.x*b.y; acc[0][2] += a.x*b.z; acc[0][3] += a.x*b.w;
            acc[1][0] += a.y*b.x; acc[1][1] += a.y*b.y; acc[1][2] += a.y*b.z; acc[1][3] += a.y*b.w;
            acc[2][0] += a.z*b.x; acc[2][1] += a.z*b.y; acc[2][2] += a.z*b.z; acc[2][3] += a.z*b.w;
            acc[3][0] += a.w*b.x; acc[3][1] += a.w*b.y; acc[3][2] += a.w*b.z; acc[3][3] += a.w*b.w;
        }
        __syncthreads();
    }

    const float4 bz = *(const float4*)&bdt[n0 + tn];
    #pragma unroll
    for (int i = 0; i < 4; ++i) {
        const int gm = m0 + tm + i;
        float4 o;
        o.x = softplus20(acc[i][0] + bz.x);
        o.y = softplus20(acc[i][1] + bz.y);
        o.z = softplus20(acc[i][2] + bz.z);
        o.w = softplus20(acc[i][3] + bz.w);
        *(float4*)&dtb[(size_t)gm * DIN + n0 + tn] = o;
    }
}

// ---------------------------------------------------------------------------
// k3: SSM update + readout with FULLY COALESCED h/A_log reads.
// Wave handles 64 channels of one batch. Instruction q: lane 4j+v loads the
// float4 at slab + q*1024B + lane*16B  ->  channel c = q*16+j, states 4v..4v+3.
// Every h/A_log wave-load is 1 KB contiguous. n-sum finished by a 4-lane
// __shfl_xor reduction; lanes v==0 store 16 consecutive floats of y.
// ---------------------------------------------------------------------------
__global__ __launch_bounds__(256) void k3_ssm(
    const float* __restrict__ dtb, const float* __restrict__ x,
    const float* __restrict__ h, const float* __restrict__ A_log,
    const float* __restrict__ Bp, const float* __restrict__ Cc,
    const float* __restrict__ Dv, float* __restrict__ y)
{
    const int t    = threadIdx.x;
    const int lane = t & 63;
    const int wv   = t >> 6;
    const int b    = blockIdx.x / 20;
    const int d0   = (blockIdx.x % 20) * 256 + wv * 64;   // 64 channels per wave

    const int v = lane & 3;    // state quad: n = 4v..4v+3
    const int j = lane >> 2;   // channel within 16

    // B/C values for this lane's 4 states (4-lane broadcast groups)
    const float4 B4 = *(const float4*)(Bp + b * NS + v * 4);
    const float4 C4 = *(const float4*)(Cc + b * NS + v * 4);

    float res[4];
    #pragma unroll
    for (int q = 0; q < 4; ++q) {
        const int c = d0 + q * 16 + j;                    // this lane's channel
        const float dtv = dtb[(size_t)b * DIN + c];
        const float xv  = x  [(size_t)b * DIN + c];
        const float dtx = dtv * xv;
        const float4 h4 = *(const float4*)(h     + ((size_t)b * DIN + c) * NS + v * 4);
        const float4 a4 = *(const float4*)(A_log + (size_t)c * NS + v * 4);
        float s;
        s  = (exp2f(dtv * (-1.442695041f * __expf(a4.x))) * h4.x + dtx * B4.x) * C4.x;
        s += (exp2f(dtv * (-1.442695041f * __expf(a4.y))) * h4.y + dtx * B4.y) * C4.y;
        s += (exp2f(dtv * (-1.442695041f * __expf(a4.z))) * h4.z + dtx * B4.z) * C4.z;
        s += (exp2f(dtv * (-1.442695041f * __expf(a4.w))) * h4.w + dtx * B4.w) * C4.w;
        if (v == 0) s += xv * Dv[c];                      // skip term added once
        res[q] = s;
    }

    // reduce the 4 state-quads (lanes 4j..4j+3) -> lane 4j
    #pragma unroll
    for (int q = 0; q < 4; ++q) {
        res[q] += __shfl_xor(res[q], 1, 64);
        res[q] += __shfl_xor(res[q], 2, 64);
    }
    if (v == 0) {
        #pragma unroll
        for (int q = 0; q < 4; ++q)
            y[(size_t)b * DIN + d0 + q * 16 + j] = res[q];
    }
}

// ---------------------------------------------------------------------------
extern "C" void kernel_launch(void* const* d_in, const int* in_sizes, int n_in,
                              void* d_out, int out_size, void* d_ws, size_t ws_size,
                              hipStream_t stream)
{
    const float* x     = (const float*)d_in[0];
    const float* h     = (const float*)d_in[1];
    const float* Wd    = (const float*)d_in[2];
    const float* Wdt   = (const float*)d_in[3];
    const float* bdt   = (const float*)d_in[4];
    const float* A_log = (const float*)d_in[5];
    const float* WB    = (const float*)d_in[6];
    const float* WC    = (const float*)d_in[7];
    const float* Dv    = (const float*)d_in[8];
    float* out = (float*)d_out;

    // ws layout (floats): psum (40x256x192) | P | Bp | Cc | dtb
    float* psum = (float*)d_ws;
    float* P    = psum + (size_t)NSPLIT * BATCH * NCAT;
    float* Bp   = P  + BATCH * RANK;
    float* Cc   = Bp + BATCH * NS;
    float* dtb  = Cc + BATCH * NS;

    // no memset needed: every ws word is written before it is read
    k1a_gemm  <<<dim3(4, 3, NSPLIT), 256, 0, stream>>>(x, Wd, WB, WC, psum);
    k1r_reduce<<<dim3(NCAT),         256, 0, stream>>>(psum, P, Bp, Cc);
    k2a_gemm  <<<dim3(4, 80),        256, 0, stream>>>(P, Wdt, bdt, dtb);
    k3_ssm    <<<dim3(BATCH * 20),   256, 0, stream>>>(dtb, x, h, A_log, Bp, Cc, Dv, out);
}